// Round 1
// baseline (286.754 us; speedup 1.0000x reference)
//
#include <hip/hip_runtime.h>
#include <stdint.h>

#define QCNT 256
#define NKEYS 10000
#define DDIM 128
#define KSEL 10
#define OBSROW 28224  // 4*84*84

// ---------------------------------------------------------------------------
// Kernel 1: one block per query. Compute sqdist to all 10000 keys, keep the
// 10 smallest with (dist, idx) lexicographic order (matches lax.top_k ties).
// Candidate encoding: u64 = (float_bits(dist) << 32) | idx. dist > 0 always
// (random normal data, dist ~ 150-400), so float bit pattern is order-
// preserving and u64 compare == lexicographic (dist, idx) compare.
// ---------------------------------------------------------------------------
__global__ __launch_bounds__(256) void knn_topk_kernel(
    const float* __restrict__ q, const float* __restrict__ k,
    int* __restrict__ out_idx) {
  const int qi  = blockIdx.x;
  const int tid = threadIdx.x;

  __shared__ float qs[DDIM];
  __shared__ unsigned long long allk[256 * KSEL];  // 20 KB
  __shared__ unsigned long long red[256];          // 2 KB
  __shared__ float q2s;

  // Stage q row in LDS (broadcast reads later are conflict-free).
  if (tid < DDIM / 4) {
    ((float4*)qs)[tid] = ((const float4*)(q + (size_t)qi * DDIM))[tid];
  }
  __syncthreads();
  if (tid == 0) {
    float s = 0.f;
    for (int j = 0; j < DDIM; ++j) s += qs[j] * qs[j];
    q2s = s;
  }
  __syncthreads();
  const float q2 = q2s;

  // Per-thread sorted top-10 (ascending). All indices compile-time constant.
  unsigned long long best[KSEL];
#pragma unroll
  for (int s = 0; s < KSEL; ++s) best[s] = ~0ULL;

  for (int n = tid; n < NKEYS; n += 256) {
    const float4* krow = (const float4*)(k + (size_t)n * DDIM);
    float dot = 0.f, k2 = 0.f;
#pragma unroll
    for (int j = 0; j < DDIM / 4; ++j) {
      float4 kv = krow[j];
      float4 qv = ((const float4*)qs)[j];
      dot += kv.x * qv.x + kv.y * qv.y + kv.z * qv.z + kv.w * qv.w;
      k2  += kv.x * kv.x + kv.y * kv.y + kv.z * kv.z + kv.w * kv.w;
    }
    float dist = q2 - 2.f * dot + k2;
    unsigned long long key =
        ((unsigned long long)__float_as_uint(dist) << 32) | (unsigned)n;
    if (key < best[KSEL - 1]) {
      best[KSEL - 1] = key;
      // one bubble pass restores sorted order; static indices only
#pragma unroll
      for (int s = KSEL - 1; s >= 1; --s) {
        if (best[s] < best[s - 1]) {
          unsigned long long t = best[s];
          best[s] = best[s - 1];
          best[s - 1] = t;
        }
      }
    }
  }

#pragma unroll
  for (int s = 0; s < KSEL; ++s) allk[tid * KSEL + s] = best[s];
  __syncthreads();

  // 10 rounds of block-wide u64-min with tombstoning.
  for (int r = 0; r < KSEL; ++r) {
    unsigned long long m = ~0ULL;
#pragma unroll
    for (int s = 0; s < KSEL; ++s) {
      unsigned long long v = allk[tid * KSEL + s];
      m = (v < m) ? v : m;
    }
    red[tid] = m;
    __syncthreads();
    for (int off = 128; off > 0; off >>= 1) {
      if (tid < off) {
        unsigned long long v = red[tid + off];
        if (v < red[tid]) red[tid] = v;
      }
      __syncthreads();
    }
    const unsigned long long winner = red[0];
    // tombstone the winner (each thread only touches its own slots)
#pragma unroll
    for (int s = 0; s < KSEL; ++s) {
      if (allk[tid * KSEL + s] == winner) allk[tid * KSEL + s] = ~0ULL;
    }
    if (tid == 0) out_idx[qi * KSEL + r] = (int)(winner & 0xffffffffu);
    __syncthreads();  // protect red[] and winner read before next round
  }
}

// ---------------------------------------------------------------------------
// Kernel 2: gather. out[r][q][:] = obs[idx[q][r]][:]. One block per output
// row (b = r*256 + q), coalesced float4 copy of 28224 floats.
// ---------------------------------------------------------------------------
__global__ __launch_bounds__(256) void knn_gather_kernel(
    const float* __restrict__ obs, const int* __restrict__ idx,
    float* __restrict__ out) {
  const int b  = blockIdx.x;   // b = r*QCNT + q
  const int r  = b / QCNT;
  const int qq = b - r * QCNT;
  const int src = idx[qq * KSEL + r];

  const float4* s = (const float4*)(obs + (size_t)src * OBSROW);
  float4*       d = (float4*)(out + (size_t)b * OBSROW);
#pragma unroll 4
  for (int i = threadIdx.x; i < OBSROW / 4; i += 256) {
    d[i] = s[i];
  }
}

extern "C" void kernel_launch(void* const* d_in, const int* in_sizes, int n_in,
                              void* d_out, int out_size, void* d_ws,
                              size_t ws_size, hipStream_t stream) {
  const float* q   = (const float*)d_in[0];  // [256,128]
  const float* k   = (const float*)d_in[1];  // [10000,128]
  const float* obs = (const float*)d_in[2];  // [10000,4,84,84]
  float* out = (float*)d_out;                // [10,256,4,84,84]
  int* idx_ws = (int*)d_ws;                  // 2560 ints

  knn_topk_kernel<<<QCNT, 256, 0, stream>>>(q, k, idx_ws);
  knn_gather_kernel<<<KSEL * QCNT, 256, 0, stream>>>(obs, idx_ws, out);
}

// Round 2
// 211.212 us; speedup vs baseline: 1.3577x; 1.3577x over previous
//
#include <hip/hip_runtime.h>
#include <stdint.h>

#define QCNT 256
#define NKEYS 10000
#define DDIM 128
#define KSEL 10
#define OBSROW 28224  // 4*84*84
#define QG 8          // queries per block in part kernel (4 waves x 2)
#define CHUNK 512     // keys per block chunk
#define NCHUNK ((NKEYS + CHUNK - 1) / CHUNK)  // 20
#define TILE 64       // keys per LDS tile
#define LIST 8        // per-lane candidate list; lane sees <=8 keys per chunk

typedef float f4v __attribute__((ext_vector_type(4)));

// Monotone (dist, idx) -> u64 encoding; handles negative dist (we drop the
// +q2 constant, so k2 - 2*dot can go negative; sign-flip trick keeps order).
__device__ inline unsigned long long enc_key(float d, int n) {
  unsigned u = __float_as_uint(d);
  u ^= (u & 0x80000000u) ? 0xFFFFFFFFu : 0x80000000u;
  return ((unsigned long long)u << 32) | (unsigned)n;
}

__device__ inline void insert8(unsigned long long best[LIST],
                               unsigned long long key) {
  if (key < best[LIST - 1]) {
    best[LIST - 1] = key;
#pragma unroll
    for (int s = LIST - 1; s >= 1; --s) {
      if (best[s] < best[s - 1]) {
        unsigned long long t = best[s];
        best[s] = best[s - 1];
        best[s - 1] = t;
      }
    }
  }
}

// ---------------------------------------------------------------------------
// Kernel 0: k2[n] = ||k_n||^2
// ---------------------------------------------------------------------------
__global__ __launch_bounds__(256) void k2_kernel(const float* __restrict__ k,
                                                 float* __restrict__ k2) {
  int n = blockIdx.x * 256 + threadIdx.x;
  if (n >= NKEYS) return;
  const float4* row = (const float4*)(k + (size_t)n * DDIM);
  float s = 0.f;
#pragma unroll
  for (int j = 0; j < DDIM / 4; ++j) {
    float4 v = row[j];
    s += v.x * v.x + v.y * v.y + v.z * v.z + v.w * v.w;
  }
  k2[n] = s;
}

// ---------------------------------------------------------------------------
// Kernel 1: partial top-10 per (query, key-chunk).
// Block = (qgroup of 8 queries) x (chunk of 512 keys). 4 waves x 2 queries.
// k staged in LDS 64-key tiles with XOR swizzle; lane owns one key per tile.
// q read via wave-uniform address (readfirstlane) -> scalar loads.
// ---------------------------------------------------------------------------
__global__ __launch_bounds__(256) void knn_part_kernel(
    const float* __restrict__ q, const float* __restrict__ k,
    const float* __restrict__ k2g, unsigned long long* __restrict__ part) {
  const int qg   = blockIdx.x;  // 0..31
  const int ch   = blockIdx.y;  // 0..19
  const int tid  = threadIdx.x;
  const int lane = tid & 63;
  const int wv   = __builtin_amdgcn_readfirstlane(tid >> 6);  // uniform 0..3

  const int kbase = ch * CHUNK;
  const int kend  = (kbase + CHUNK < NKEYS) ? kbase + CHUNK : NKEYS;

  __shared__ float4 kl[TILE][DDIM / 4];  // 32 KB, swizzled columns

  const int qA = qg * QG + 2 * wv;
  const int qB = qA + 1;
  const float4* qArow = (const float4*)(q + (size_t)qA * DDIM);
  const float4* qBrow = (const float4*)(q + (size_t)qB * DDIM);

  unsigned long long bestA[LIST], bestB[LIST];
#pragma unroll
  for (int s = 0; s < LIST; ++s) {
    bestA[s] = ~0ULL;
    bestB[s] = ~0ULL;
  }

  const int ntiles = (kend - kbase + TILE - 1) / TILE;
  for (int t = 0; t < ntiles; ++t) {
    const int tb = kbase + t * TILE;
    __syncthreads();  // previous tile's readers done before overwrite
    // stage 64 keys x 128 floats = 2048 float4; 256 threads x 8 iters.
    // LDS col swizzled: kl[row][c ^ (row&7)] = k[row][c]
#pragma unroll
    for (int it = 0; it < (TILE * DDIM / 4) / 256; ++it) {
      int l   = tid + it * 256;
      int row = l >> 5;  // 0..63
      int c   = l & 31;
      int n   = tb + row;
      if (n < NKEYS) {
        kl[row][c ^ (row & 7)] = ((const float4*)(k + (size_t)n * DDIM))[c];
      }
    }
    __syncthreads();

    const int n = tb + lane;  // this lane's key
    if (n < kend) {
      float dA = 0.f, dB = 0.f;
#pragma unroll
      for (int j = 0; j < DDIM / 4; ++j) {
        float4 kv = kl[lane][j ^ (lane & 7)];
        float4 qa = qArow[j];  // uniform addr -> s_load
        float4 qb = qBrow[j];
        dA = fmaf(kv.x, qa.x, dA);
        dA = fmaf(kv.y, qa.y, dA);
        dA = fmaf(kv.z, qa.z, dA);
        dA = fmaf(kv.w, qa.w, dA);
        dB = fmaf(kv.x, qb.x, dB);
        dB = fmaf(kv.y, qb.y, dB);
        dB = fmaf(kv.z, qb.z, dB);
        dB = fmaf(kv.w, qb.w, dB);
      }
      float k2v = k2g[n];
      insert8(bestA, enc_key(fmaf(-2.f, dA, k2v), n));
      insert8(bestB, enc_key(fmaf(-2.f, dB, k2v), n));
    }
  }

  // Wave-level tombstone extraction: 10 rounds of u64 wave-min. Each lane's
  // list is sorted ascending, so its candidate is best[0]; the unique winner
  // lane shifts its list down (static indices only).
  unsigned long long* dstA = part + ((size_t)qA * NCHUNK + ch) * KSEL;
  unsigned long long* dstB = part + ((size_t)qB * NCHUNK + ch) * KSEL;

#pragma unroll 1
  for (int r = 0; r < KSEL; ++r) {
    unsigned long long w = bestA[0];
#pragma unroll
    for (int off = 1; off < 64; off <<= 1) {
      unsigned long long o =
          (unsigned long long)__shfl_xor((long long)w, off, 64);
      if (o < w) w = o;
    }
    if (bestA[0] == w) {
#pragma unroll
      for (int s = 0; s < LIST - 1; ++s) bestA[s] = bestA[s + 1];
      bestA[LIST - 1] = ~0ULL;
    }
    if (lane == 0) dstA[r] = w;
  }
#pragma unroll 1
  for (int r = 0; r < KSEL; ++r) {
    unsigned long long w = bestB[0];
#pragma unroll
    for (int off = 1; off < 64; off <<= 1) {
      unsigned long long o =
          (unsigned long long)__shfl_xor((long long)w, off, 64);
      if (o < w) w = o;
    }
    if (bestB[0] == w) {
#pragma unroll
      for (int s = 0; s < LIST - 1; ++s) bestB[s] = bestB[s + 1];
      bestB[LIST - 1] = ~0ULL;
    }
    if (lane == 0) dstB[r] = w;
  }
}

// ---------------------------------------------------------------------------
// Kernel 2: merge 20 partial top-10 lists per query -> final 10 indices.
// One block per query; 200 candidates; 10 rounds of block-min + tombstone.
// ---------------------------------------------------------------------------
__global__ __launch_bounds__(256) void knn_merge_kernel(
    const unsigned long long* __restrict__ part, int* __restrict__ out_idx) {
  const int qq  = blockIdx.x;
  const int tid = threadIdx.x;
  __shared__ unsigned long long red[256];
  const int NC = NCHUNK * KSEL;  // 200
  unsigned long long mine =
      (tid < NC) ? part[(size_t)qq * NC + tid] : ~0ULL;
  for (int r = 0; r < KSEL; ++r) {
    red[tid] = mine;
    __syncthreads();
    for (int off = 128; off > 0; off >>= 1) {
      if (tid < off) {
        unsigned long long v = red[tid + off];
        if (v < red[tid]) red[tid] = v;
      }
      __syncthreads();
    }
    unsigned long long w = red[0];
    __syncthreads();  // all reads of red[0] done before next-round writes
    if (mine == w) mine = ~0ULL;
    if (tid == 0) out_idx[qq * KSEL + r] = (int)(w & 0xffffffffu);
  }
}

// ---------------------------------------------------------------------------
// Kernel 3: gather. out[r][q][:] = obs[idx[q][r]][:]. Non-temporal copy.
// ---------------------------------------------------------------------------
__global__ __launch_bounds__(256) void knn_gather_kernel(
    const float* __restrict__ obs, const int* __restrict__ idx,
    float* __restrict__ out) {
  const int b   = blockIdx.x;  // b = r*QCNT + q
  const int r   = b / QCNT;
  const int qq  = b - r * QCNT;
  const int src = idx[qq * KSEL + r];

  const f4v* s = (const f4v*)(obs + (size_t)src * OBSROW);
  f4v*       d = (f4v*)(out + (size_t)b * OBSROW);
#pragma unroll 4
  for (int i = threadIdx.x; i < OBSROW / 4; i += 256) {
    f4v v = __builtin_nontemporal_load(&s[i]);
    __builtin_nontemporal_store(v, &d[i]);
  }
}

extern "C" void kernel_launch(void* const* d_in, const int* in_sizes, int n_in,
                              void* d_out, int out_size, void* d_ws,
                              size_t ws_size, hipStream_t stream) {
  const float* q   = (const float*)d_in[0];  // [256,128]
  const float* k   = (const float*)d_in[1];  // [10000,128]
  const float* obs = (const float*)d_in[2];  // [10000,4,84,84]
  float* out = (float*)d_out;                // [10,256,4,84,84]

  // ws layout
  float* k2 = (float*)d_ws;                                   // 40000 B
  unsigned long long* part =
      (unsigned long long*)((char*)d_ws + 40960);             // 409600 B
  int* idx_ws = (int*)((char*)d_ws + 40960 + 409600);         // 10240 B

  k2_kernel<<<(NKEYS + 255) / 256, 256, 0, stream>>>(k, k2);
  knn_part_kernel<<<dim3(QCNT / QG, NCHUNK), 256, 0, stream>>>(q, k, k2, part);
  knn_merge_kernel<<<QCNT, 256, 0, stream>>>(part, idx_ws);
  knn_gather_kernel<<<KSEL * QCNT, 256, 0, stream>>>(obs, idx_ws, out);
}

// Round 3
// 175.111 us; speedup vs baseline: 1.6376x; 1.2062x over previous
//
#include <hip/hip_runtime.h>
#include <stdint.h>

#define QCNT 256
#define NKEYS 10000
#define DDIM 128
#define KSEL 10
#define OBSROW 28224  // 4*84*84
#define QG 8          // queries per block in part kernel (4 waves x 2)
#define CHUNK 512     // keys per block chunk
#define NCHUNK ((NKEYS + CHUNK - 1) / CHUNK)  // 20
#define TILE 64       // keys per LDS tile
#define LIST 8        // per-lane candidate list; lane sees <=8 keys per chunk
#define NCAND (NCHUNK * KSEL)  // 200 candidates per query

typedef float f4v __attribute__((ext_vector_type(4)));

// Monotone (dist, idx) -> u64 encoding; dist = k2 - 2*dot can be negative
// (q2 constant dropped); sign-flip trick keeps total order.
__device__ inline unsigned long long enc_key(float d, int n) {
  unsigned u = __float_as_uint(d);
  u ^= (unsigned)((int)u >> 31) | 0x80000000u;
  return ((unsigned long long)u << 32) | (unsigned)n;
}

__device__ inline void insert8(unsigned long long best[LIST],
                               unsigned long long key) {
  if (key < best[LIST - 1]) {
    best[LIST - 1] = key;
#pragma unroll
    for (int s = LIST - 1; s >= 1; --s) {
      if (best[s] < best[s - 1]) {
        unsigned long long t = best[s];
        best[s] = best[s - 1];
        best[s - 1] = t;
      }
    }
  }
}

__device__ inline unsigned long long wave_min_u64(unsigned long long w) {
#pragma unroll
  for (int off = 1; off < 64; off <<= 1) {
    unsigned long long o =
        (unsigned long long)__shfl_xor((long long)w, off, 64);
    if (o < w) w = o;
  }
  return w;
}

// ---------------------------------------------------------------------------
// Kernel 1: partial top-10 per (query-group, key-chunk). k2 fused in-loop.
// Block = 8 queries x 512 keys; 4 waves x 2 queries; k staged in 64-key LDS
// tiles (XOR-swizzled columns); q read via wave-uniform addr -> scalar loads.
// ---------------------------------------------------------------------------
__global__ __launch_bounds__(256) void knn_part_kernel(
    const float* __restrict__ q, const float* __restrict__ k,
    unsigned long long* __restrict__ part) {
  const int qg   = blockIdx.x;  // 0..31
  const int ch   = blockIdx.y;  // 0..19
  const int tid  = threadIdx.x;
  const int lane = tid & 63;
  const int wv   = __builtin_amdgcn_readfirstlane(tid >> 6);  // uniform 0..3

  const int kbase = ch * CHUNK;
  const int kend  = (kbase + CHUNK < NKEYS) ? kbase + CHUNK : NKEYS;

  __shared__ float4 kl[TILE][DDIM / 4];  // 32 KB, swizzled columns

  const int qA = qg * QG + 2 * wv;
  const int qB = qA + 1;
  const float4* qArow = (const float4*)(q + (size_t)qA * DDIM);
  const float4* qBrow = (const float4*)(q + (size_t)qB * DDIM);

  unsigned long long bestA[LIST], bestB[LIST];
#pragma unroll
  for (int s = 0; s < LIST; ++s) {
    bestA[s] = ~0ULL;
    bestB[s] = ~0ULL;
  }

  const int ntiles = (kend - kbase + TILE - 1) / TILE;
  for (int t = 0; t < ntiles; ++t) {
    const int tb = kbase + t * TILE;
    __syncthreads();  // previous tile's readers done before overwrite
#pragma unroll
    for (int it = 0; it < (TILE * DDIM / 4) / 256; ++it) {
      int l   = tid + it * 256;
      int row = l >> 5;  // 0..63
      int c   = l & 31;
      int n   = tb + row;
      if (n < NKEYS) {
        kl[row][c ^ (row & 7)] = ((const float4*)(k + (size_t)n * DDIM))[c];
      }
    }
    __syncthreads();

    const int n = tb + lane;  // this lane's key
    if (n < kend) {
      float dA = 0.f, dB = 0.f, kk = 0.f;
#pragma unroll
      for (int j = 0; j < DDIM / 4; ++j) {
        float4 kv = kl[lane][j ^ (lane & 7)];
        float4 qa = qArow[j];  // uniform addr -> s_load
        float4 qb = qBrow[j];
        dA = fmaf(kv.x, qa.x, dA);
        dA = fmaf(kv.y, qa.y, dA);
        dA = fmaf(kv.z, qa.z, dA);
        dA = fmaf(kv.w, qa.w, dA);
        dB = fmaf(kv.x, qb.x, dB);
        dB = fmaf(kv.y, qb.y, dB);
        dB = fmaf(kv.z, qb.z, dB);
        dB = fmaf(kv.w, qb.w, dB);
        kk = fmaf(kv.x, kv.x, kk);
        kk = fmaf(kv.y, kv.y, kk);
        kk = fmaf(kv.z, kv.z, kk);
        kk = fmaf(kv.w, kv.w, kk);
      }
      insert8(bestA, enc_key(fmaf(-2.f, dA, kk), n));
      insert8(bestB, enc_key(fmaf(-2.f, dB, kk), n));
    }
  }

  // Wave-level tombstone extraction: 10 rounds of u64 wave-min; lanes' lists
  // are sorted ascending so best[0] is each lane's candidate.
  unsigned long long* dstA = part + ((size_t)qA * NCHUNK + ch) * KSEL;
  unsigned long long* dstB = part + ((size_t)qB * NCHUNK + ch) * KSEL;

#pragma unroll 1
  for (int r = 0; r < KSEL; ++r) {
    unsigned long long w = wave_min_u64(bestA[0]);
    if (bestA[0] == w) {
#pragma unroll
      for (int s = 0; s < LIST - 1; ++s) bestA[s] = bestA[s + 1];
      bestA[LIST - 1] = ~0ULL;
    }
    if (lane == 0) dstA[r] = w;
  }
#pragma unroll 1
  for (int r = 0; r < KSEL; ++r) {
    unsigned long long w = wave_min_u64(bestB[0]);
    if (bestB[0] == w) {
#pragma unroll
      for (int s = 0; s < LIST - 1; ++s) bestB[s] = bestB[s + 1];
      bestB[LIST - 1] = ~0ULL;
    }
    if (lane == 0) dstB[r] = w;
  }
}

// ---------------------------------------------------------------------------
// Kernel 2: fused merge + gather. Block b = r*QCNT + q. Wave 0 extracts the
// r-th smallest of the query's 200 candidates in registers (tombstone rounds
// of 64-lane u64 butterfly-min), then the whole block copies the obs row.
// Redundant 10x merge per query is VALU-only and hides under HBM traffic.
// ---------------------------------------------------------------------------
__global__ __launch_bounds__(256) void knn_merge_gather_kernel(
    const float* __restrict__ obs, const unsigned long long* __restrict__ part,
    float* __restrict__ out) {
  const int b   = blockIdx.x;  // b = r*QCNT + q
  const int r   = b / QCNT;
  const int qq  = b - r * QCNT;
  const int tid = threadIdx.x;

  __shared__ int s_src;

  if (tid < 64) {
    const unsigned long long* cp = part + (size_t)qq * NCAND;
    // lane holds candidates tid, tid+64, tid+128 (tid+192 only for tid<8)
    unsigned long long c0 = cp[tid];
    unsigned long long c1 = cp[tid + 64];
    unsigned long long c2 = (tid + 128 < NCAND) ? cp[tid + 128] : ~0ULL;
    unsigned long long c3 = (tid + 192 < NCAND) ? cp[tid + 192] : ~0ULL;
    unsigned long long w = ~0ULL;
#pragma unroll 1
    for (int round = 0; round <= r; ++round) {
      unsigned long long m = c0;
      m = (c1 < m) ? c1 : m;
      m = (c2 < m) ? c2 : m;
      m = (c3 < m) ? c3 : m;
      w = wave_min_u64(m);
      if (c0 == w) c0 = ~0ULL;
      if (c1 == w) c1 = ~0ULL;
      if (c2 == w) c2 = ~0ULL;
      if (c3 == w) c3 = ~0ULL;
    }
    if (tid == 0) s_src = (int)(w & 0xffffffffu);
  }
  __syncthreads();
  const int src = s_src;

  const f4v* s = (const f4v*)(obs + (size_t)src * OBSROW);
  f4v*       d = (f4v*)(out + (size_t)b * OBSROW);
#pragma unroll 4
  for (int i = tid; i < OBSROW / 4; i += 256) {
    f4v v = s[i];  // cached load: L3 catches duplicate rows
    __builtin_nontemporal_store(v, &d[i]);
  }
}

extern "C" void kernel_launch(void* const* d_in, const int* in_sizes, int n_in,
                              void* d_out, int out_size, void* d_ws,
                              size_t ws_size, hipStream_t stream) {
  const float* q   = (const float*)d_in[0];  // [256,128]
  const float* k   = (const float*)d_in[1];  // [10000,128]
  const float* obs = (const float*)d_in[2];  // [10000,4,84,84]
  float* out = (float*)d_out;                // [10,256,4,84,84]

  unsigned long long* part = (unsigned long long*)d_ws;  // 409600 B

  knn_part_kernel<<<dim3(QCNT / QG, NCHUNK), 256, 0, stream>>>(q, k, part);
  knn_merge_gather_kernel<<<KSEL * QCNT, 256, 0, stream>>>(obs, part, out);
}